// Round 2
// baseline (888.053 us; speedup 1.0000x reference)
//
#include <hip/hip_runtime.h>
#include <hip/hip_bf16.h>

#define N_ENT   50000
#define N_EDGES 800000
#define DIM     128
#define BATCH   1024

typedef __attribute__((ext_vector_type(8))) short  short8;
typedef __attribute__((ext_vector_type(4))) float  float4v;
using bf16 = __hip_bfloat16;

static __device__ __forceinline__ float b2f(bf16 v){ return __bfloat162float(v); }
static __device__ __forceinline__ short bbits(bf16 v){ return __builtin_bit_cast(short, v); }

// ---------------- CSR build ----------------
__global__ void k_hist(const int* __restrict__ rows, int* __restrict__ deg){
    int e = blockIdx.x*256 + threadIdx.x;
    if(e < N_EDGES) atomicAdd(&deg[rows[e]], 1);
}

__global__ void k_scan(const int* __restrict__ deg, int* __restrict__ row_start){
    __shared__ int part[1024];
    const int CH = 49;                       // 1024*49 = 50176 >= 50001
    int t = threadIdx.x;
    int base = t*CH;
    int s = 0;
    for(int i=0;i<CH;i++){ int idx=base+i; if(idx<N_ENT) s += deg[idx]; }
    part[t]=s; __syncthreads();
    for(int off=1; off<1024; off<<=1){
        int v = part[t];
        int add = (t>=off)? part[t-off] : 0;
        __syncthreads();
        part[t] = v+add;
        __syncthreads();
    }
    int run = part[t]-s;                     // exclusive prefix of this chunk
    for(int i=0;i<CH;i++){
        int idx=base+i;
        if(idx<=N_ENT){
            row_start[idx]=run;
            if(idx<N_ENT) run += deg[idx];
        }
    }
}

__global__ void k_scatter(const int* __restrict__ rows, const int* __restrict__ cols,
                          const float* __restrict__ vals, const int* __restrict__ row_start,
                          int* __restrict__ cursor, int* __restrict__ csr_col,
                          float* __restrict__ csr_val){
    int e = blockIdx.x*256 + threadIdx.x;
    if(e >= N_EDGES) return;
    int r = rows[e];
    int pos = row_start[r] + atomicAdd(&cursor[r], 1);
    csr_col[pos] = cols[e];
    csr_val[pos] = vals[e];
}

// transpose W1/W2 (fp32) -> bf16 hi/lo at [n][k] layout for contiguous B-fragments
__global__ void k_prep(const float* __restrict__ W1, const float* __restrict__ W2,
                       bf16* __restrict__ W1T_hi, bf16* __restrict__ W1T_lo,
                       bf16* __restrict__ W2T_hi, bf16* __restrict__ W2T_lo){
    int i = blockIdx.x*256 + threadIdx.x;    // 32768 threads
    const float* src = (i < 16384) ? W1 : W2;
    bf16* dh = (i < 16384) ? W1T_hi : W2T_hi;
    bf16* dl = (i < 16384) ? W1T_lo : W2T_lo;
    int j = i & 16383;
    int d = j >> 7, c = j & 127;
    float f = src[j];
    bf16 h = __float2bfloat16(f);
    dh[c*DIM + d] = h;
    dl[c*DIM + d] = __float2bfloat16(f - b2f(h));
}

// ---------------- mm1: t = E[init_ind] @ W1, A split in-register ----------------
__global__ __launch_bounds__(256) void k_mm1(const float* __restrict__ E,
                                             const int* __restrict__ init_ind,
                                             const bf16* __restrict__ WT_hi,
                                             const bf16* __restrict__ WT_lo,
                                             float* __restrict__ out){
    int wave = threadIdx.x >> 6, lane = threadIdx.x & 63;
    int mt = blockIdx.x*4 + wave;
    if(mt >= 3125) return;
    int m = lane & 15, q = lane >> 4;
    int row = init_ind[mt*16 + m];
    const float* ap = E + row*DIM + q*8;
    float4v acc[8];
    #pragma unroll
    for(int i=0;i<8;i++) acc[i] = (float4v){0.f,0.f,0.f,0.f};
    #pragma unroll
    for(int ks=0; ks<4; ks++){
        float4v u0 = *(const float4v*)(ap + ks*32);
        float4v u1 = *(const float4v*)(ap + ks*32 + 4);
        short8 ah, al;
        #pragma unroll
        for(int j=0;j<8;j++){
            float fv = (j<4) ? u0[j] : u1[j-4];
            bf16 h = __float2bfloat16(fv);
            ah[j] = bbits(h);
            al[j] = bbits(__float2bfloat16(fv - b2f(h)));
        }
        #pragma unroll
        for(int nt=0; nt<8; nt++){
            short8 bh = *(const short8*)(WT_hi + (nt*16 + m)*DIM + ks*32 + q*8);
            short8 bl = *(const short8*)(WT_lo + (nt*16 + m)*DIM + ks*32 + q*8);
            acc[nt] = __builtin_amdgcn_mfma_f32_16x16x32_bf16(ah, bh, acc[nt], 0,0,0);
            acc[nt] = __builtin_amdgcn_mfma_f32_16x16x32_bf16(ah, bl, acc[nt], 0,0,0);
            acc[nt] = __builtin_amdgcn_mfma_f32_16x16x32_bf16(al, bh, acc[nt], 0,0,0);
        }
    }
    #pragma unroll
    for(int nt=0; nt<8; nt++)
        #pragma unroll
        for(int r=0;r<4;r++)
            out[(mt*16 + q*4 + r)*DIM + nt*16 + m] = acc[nt][r];
}

// ---------------- mm2: t = h @ W2, A pre-split, B split: 3 MFMA ----------------
__global__ __launch_bounds__(256) void k_mm2(const bf16* __restrict__ h_hi,
                                             const bf16* __restrict__ h_lo,
                                             const bf16* __restrict__ WT_hi,
                                             const bf16* __restrict__ WT_lo,
                                             float* __restrict__ out){
    int wave = threadIdx.x >> 6, lane = threadIdx.x & 63;
    int mt = blockIdx.x*4 + wave;
    if(mt >= 3125) return;
    int m = lane & 15, q = lane >> 4;
    int row = mt*16 + m;
    const bf16* ah_p = h_hi + row*DIM + q*8;
    const bf16* al_p = h_lo + row*DIM + q*8;
    float4v acc[8];
    #pragma unroll
    for(int i=0;i<8;i++) acc[i] = (float4v){0.f,0.f,0.f,0.f};
    #pragma unroll
    for(int ks=0; ks<4; ks++){
        short8 ah = *(const short8*)(ah_p + ks*32);
        short8 al = *(const short8*)(al_p + ks*32);
        #pragma unroll
        for(int nt=0; nt<8; nt++){
            short8 bh = *(const short8*)(WT_hi + (nt*16 + m)*DIM + ks*32 + q*8);
            short8 bl = *(const short8*)(WT_lo + (nt*16 + m)*DIM + ks*32 + q*8);
            acc[nt] = __builtin_amdgcn_mfma_f32_16x16x32_bf16(ah, bh, acc[nt], 0,0,0);
            acc[nt] = __builtin_amdgcn_mfma_f32_16x16x32_bf16(ah, bl, acc[nt], 0,0,0);
            acc[nt] = __builtin_amdgcn_mfma_f32_16x16x32_bf16(al, bh, acc[nt], 0,0,0);
        }
    }
    #pragma unroll
    for(int nt=0; nt<8; nt++)
        #pragma unroll
        for(int r=0;r<4;r++)
            out[(mt*16 + q*4 + r)*DIM + nt*16 + m] = acc[nt][r];
}

// ---------------- SpMM: one wave per row, 2 fp32 acc per lane ----------------
__global__ __launch_bounds__(256) void k_spmm1(const float* __restrict__ t,
        const int* __restrict__ row_start, const int* __restrict__ csr_col,
        const float* __restrict__ csr_val, const float* __restrict__ b1,
        bf16* __restrict__ h_hi, bf16* __restrict__ h_lo){
    int wave = threadIdx.x>>6, lane = threadIdx.x&63;
    int i = blockIdx.x*4 + wave;
    if(i >= N_ENT) return;
    int e0 = row_start[i], e1 = row_start[i+1];
    float a0=0.f, a1=0.f;
    for(int e=e0;e<e1;e++){
        int c = csr_col[e]; float v = csr_val[e];
        a0 += v * t[c*DIM + lane];
        a1 += v * t[c*DIM + 64 + lane];
    }
    float r0 = fmaxf(a0 + b1[lane],    0.f);
    float r1 = fmaxf(a1 + b1[64+lane], 0.f);
    bf16 h0 = __float2bfloat16(r0);
    bf16 h1 = __float2bfloat16(r1);
    h_hi[i*DIM+lane]    = h0;  h_lo[i*DIM+lane]    = __float2bfloat16(r0 - b2f(h0));
    h_hi[i*DIM+64+lane] = h1;  h_lo[i*DIM+64+lane] = __float2bfloat16(r1 - b2f(h1));
}

// spmm2 + residual (final = E[init_ind] + relu(...)), write hi/lo split of final
__global__ __launch_bounds__(256) void k_spmm2(const float* __restrict__ t,
        const int* __restrict__ row_start, const int* __restrict__ csr_col,
        const float* __restrict__ csr_val, const float* __restrict__ b2_,
        const float* __restrict__ E, const int* __restrict__ init_ind,
        bf16* __restrict__ fe_hi, bf16* __restrict__ fe_lo){
    int wave = threadIdx.x>>6, lane = threadIdx.x&63;
    int i = blockIdx.x*4 + wave;
    if(i >= N_ENT) return;
    int e0 = row_start[i], e1 = row_start[i+1];
    float a0=0.f, a1=0.f;
    for(int e=e0;e<e1;e++){
        int c = csr_col[e]; float v = csr_val[e];
        a0 += v * t[c*DIM + lane];
        a1 += v * t[c*DIM + 64 + lane];
    }
    int erow = init_ind[i];
    float f0 = E[erow*DIM + lane]    + fmaxf(a0 + b2_[lane],    0.f);
    float f1 = E[erow*DIM + 64+lane] + fmaxf(a1 + b2_[64+lane], 0.f);
    bf16 g0 = __float2bfloat16(f0);
    bf16 g1 = __float2bfloat16(f1);
    fe_hi[i*DIM+lane]    = g0;  fe_lo[i*DIM+lane]    = __float2bfloat16(f0 - b2f(g0));
    fe_hi[i*DIM+64+lane] = g1;  fe_lo[i*DIM+64+lane] = __float2bfloat16(f1 - b2f(g1));
}

// ---------------- vm = bn1(bn0(final[head]) * (R[rel]@W)) ----------------
__global__ __launch_bounds__(128) void k_vm(const float* __restrict__ R_emb,
        const float* __restrict__ W, const int* __restrict__ head,
        const int* __restrict__ rel, const bf16* __restrict__ fe_hi,
        const bf16* __restrict__ fe_lo, const float* __restrict__ g0v,
        const float* __restrict__ be0, const float* __restrict__ g1v,
        const float* __restrict__ be1, bf16* __restrict__ vm_hi,
        bf16* __restrict__ vm_lo){
    int b = blockIdx.x; int j = threadIdx.x;
    __shared__ float rs[DIM];
    int rid = rel[b], hid = head[b];
    rs[j] = R_emb[rid*DIM + j];
    __syncthreads();
    float acc = 0.f;
    #pragma unroll 8
    for(int d=0; d<DIM; d++) acc += rs[d] * W[d*DIM + j];
    const float inv = rsqrtf(1.f + 1e-5f);
    float fe = b2f(fe_hi[hid*DIM+j]) + b2f(fe_lo[hid*DIM+j]);
    float x  = fe * (g0v[j] * inv) + be0[j];
    float vm = (x * acc) * (g1v[j] * inv) + be1[j];
    bf16 hi = __float2bfloat16(vm);
    vm_hi[b*DIM+j] = hi;
    vm_lo[b*DIM+j] = __float2bfloat16(vm - b2f(hi));
}

// ---------------- big GEMM: out = sigmoid(vm @ fe^T), split-bf16 x3 ----------------
__global__ __launch_bounds__(256) void k_big(const bf16* __restrict__ vm_hi,
        const bf16* __restrict__ vm_lo, const bf16* __restrict__ fe_hi,
        const bf16* __restrict__ fe_lo, float* __restrict__ out){
    int wave = threadIdx.x>>6, lane = threadIdx.x&63;
    int m = lane&15, q = lane>>4;
    int b0 = blockIdx.y * 64;
    int n0 = blockIdx.x * 64 + wave*16;
    int nrow = n0 + m;
    int ncl = nrow < N_ENT ? nrow : N_ENT-1;
    const bf16* fh = fe_hi + ncl*DIM + q*8;
    const bf16* fl = fe_lo + ncl*DIM + q*8;
    float4v acc[4];
    #pragma unroll
    for(int i=0;i<4;i++) acc[i] = (float4v){0.f,0.f,0.f,0.f};
    #pragma unroll
    for(int ks=0; ks<4; ks++){
        short8 bh = *(const short8*)(fh + ks*32);
        short8 bl = *(const short8*)(fl + ks*32);
        #pragma unroll
        for(int mt=0; mt<4; mt++){
            const bf16* vh = vm_hi + (b0 + mt*16 + m)*DIM + ks*32 + q*8;
            const bf16* vl = vm_lo + (b0 + mt*16 + m)*DIM + ks*32 + q*8;
            short8 ah = *(const short8*)vh;
            short8 al = *(const short8*)vl;
            acc[mt] = __builtin_amdgcn_mfma_f32_16x16x32_bf16(ah, bh, acc[mt], 0,0,0);
            acc[mt] = __builtin_amdgcn_mfma_f32_16x16x32_bf16(ah, bl, acc[mt], 0,0,0);
            acc[mt] = __builtin_amdgcn_mfma_f32_16x16x32_bf16(al, bh, acc[mt], 0,0,0);
        }
    }
    int on = n0 + m;
    if(on >= N_ENT) return;
    #pragma unroll
    for(int mt=0;mt<4;mt++)
        #pragma unroll
        for(int r=0;r<4;r++){
            int ob = b0 + mt*16 + q*4 + r;
            float d = acc[mt][r];
            float s = 1.f/(1.f + __expf(-d));
            out[(long)ob*N_ENT + on] = s;
        }
}

extern "C" void kernel_launch(void* const* d_in, const int* in_sizes, int n_in,
                              void* d_out, int out_size, void* d_ws, size_t ws_size,
                              hipStream_t stream) {
    const float* E     = (const float*)d_in[0];
    const float* R_emb = (const float*)d_in[1];
    const float* W1    = (const float*)d_in[2];
    const float* b1    = (const float*)d_in[3];
    const float* W2    = (const float*)d_in[4];
    const float* b2_   = (const float*)d_in[5];
    const float* W     = (const float*)d_in[6];
    const float* vals  = (const float*)d_in[7];
    const float* g0v   = (const float*)d_in[8];
    const float* be0   = (const float*)d_in[9];
    const float* g1v   = (const float*)d_in[10];
    const float* be1   = (const float*)d_in[11];
    const int* head    = (const int*)d_in[12];
    const int* rel     = (const int*)d_in[13];
    const int* init_ind= (const int*)d_in[14];
    const int* rows    = (const int*)d_in[15];
    const int* cols    = (const int*)d_in[16];
    float* out = (float*)d_out;

    char* w = (char*)d_ws;
    int*   deg       = (int*)  (w + 0);
    int*   cursor    = (int*)  (w + 200000);
    int*   row_start = (int*)  (w + 400000);
    int*   csr_col   = (int*)  (w + 600064);
    float* csr_val   = (float*)(w + 3800064);
    bf16*  W1T_hi    = (bf16*) (w + 7000064);
    bf16*  W1T_lo    = (bf16*) (w + 7032832);
    bf16*  W2T_hi    = (bf16*) (w + 7065600);
    bf16*  W2T_lo    = (bf16*) (w + 7098368);
    float* t         = (float*)(w + 7131136);    // 25.6 MB
    bf16*  h_hi      = (bf16*) (w + 32731136);
    bf16*  h_lo      = (bf16*) (w + 45531136);
    bf16*  fe_hi     = (bf16*) (w + 58331136);
    bf16*  fe_lo     = (bf16*) (w + 71131136);
    bf16*  vm_hi     = (bf16*) (w + 83931136);
    bf16*  vm_lo     = (bf16*) (w + 84193280);
    // end ~84.5 MB

    hipMemsetAsync(deg, 0, 2*N_ENT*sizeof(int), stream);   // deg + cursor
    k_hist    <<<3125, 256, 0, stream>>>(rows, deg);
    k_scan    <<<1, 1024, 0, stream>>>(deg, row_start);
    k_scatter <<<3125, 256, 0, stream>>>(rows, cols, vals, row_start, cursor, csr_col, csr_val);
    k_prep    <<<128, 256, 0, stream>>>(W1, W2, W1T_hi, W1T_lo, W2T_hi, W2T_lo);
    k_mm1     <<<782, 256, 0, stream>>>(E, init_ind, W1T_hi, W1T_lo, t);
    k_spmm1   <<<12500, 256, 0, stream>>>(t, row_start, csr_col, csr_val, b1, h_hi, h_lo);
    k_mm2     <<<782, 256, 0, stream>>>(h_hi, h_lo, W2T_hi, W2T_lo, t);
    k_spmm2   <<<12500, 256, 0, stream>>>(t, row_start, csr_col, csr_val, b2_, E, init_ind, fe_hi, fe_lo);
    k_vm      <<<BATCH, 128, 0, stream>>>(R_emb, W, head, rel, fe_hi, fe_lo, g0v, be0, g1v, be1, vm_hi, vm_lo);
    k_big     <<<dim3(782, 16), 256, 0, stream>>>(vm_hi, vm_lo, fe_hi, fe_lo, out);
}

// Round 3
// 637.667 us; speedup vs baseline: 1.3927x; 1.3927x over previous
//
#include <hip/hip_runtime.h>

#define N_ENT   50000
#define N_EDGES 800000
#define DIM     128
#define BATCH   1024

typedef _Float16 half_t;
typedef __attribute__((ext_vector_type(8))) _Float16 half8;
typedef __attribute__((ext_vector_type(2))) _Float16 half2v;
typedef __attribute__((ext_vector_type(4))) float float4v;
typedef __attribute__((ext_vector_type(2))) float float2v;

// ---------------- CSR build ----------------
__global__ void k_hist(const int* __restrict__ rows, int* __restrict__ deg){
    int e = blockIdx.x*256 + threadIdx.x;
    if(e < N_EDGES) atomicAdd(&deg[rows[e]], 1);
}

__global__ void k_scan(const int* __restrict__ deg, int* __restrict__ row_start){
    __shared__ int part[1024];
    const int CH = 49;                       // 1024*49 = 50176 >= 50001
    int t = threadIdx.x;
    int base = t*CH;
    int s = 0;
    for(int i=0;i<CH;i++){ int idx=base+i; if(idx<N_ENT) s += deg[idx]; }
    part[t]=s; __syncthreads();
    for(int off=1; off<1024; off<<=1){
        int v = part[t];
        int add = (t>=off)? part[t-off] : 0;
        __syncthreads();
        part[t] = v+add;
        __syncthreads();
    }
    int run = part[t]-s;
    for(int i=0;i<CH;i++){
        int idx=base+i;
        if(idx<=N_ENT){
            row_start[idx]=run;
            if(idx<N_ENT) run += deg[idx];
        }
    }
}

__global__ void k_scatter(const int* __restrict__ rows, const int* __restrict__ cols,
                          const float* __restrict__ vals, const int* __restrict__ row_start,
                          int* __restrict__ cursor, int* __restrict__ csr_col,
                          float* __restrict__ csr_val){
    int e = blockIdx.x*256 + threadIdx.x;
    if(e >= N_EDGES) return;
    int r = rows[e];
    int pos = row_start[r] + atomicAdd(&cursor[r], 1);
    csr_col[pos] = cols[e];
    csr_val[pos] = vals[e];
}

// transpose W1/W2 (fp32) -> fp16 hi/lo at [n][k] layout for contiguous B-fragments
__global__ void k_prep(const float* __restrict__ W1, const float* __restrict__ W2,
                       half_t* __restrict__ W1T_hi, half_t* __restrict__ W1T_lo,
                       half_t* __restrict__ W2T_hi, half_t* __restrict__ W2T_lo){
    int i = blockIdx.x*256 + threadIdx.x;    // 32768 threads
    const float* src = (i < 16384) ? W1 : W2;
    half_t* dh = (i < 16384) ? W1T_hi : W2T_hi;
    half_t* dl = (i < 16384) ? W1T_lo : W2T_lo;
    int j = i & 16383;
    int d = j >> 7, c = j & 127;
    float f = src[j];
    half_t h = (half_t)f;
    dh[c*DIM + d] = h;
    dl[c*DIM + d] = (half_t)(f - (float)h);
}

// ---------------- mm1: t = E[init_ind] @ W1 (3-term split fp16), out fp16 ----------------
__global__ __launch_bounds__(256) void k_mm1(const float* __restrict__ E,
                                             const int* __restrict__ init_ind,
                                             const half_t* __restrict__ WT_hi,
                                             const half_t* __restrict__ WT_lo,
                                             half_t* __restrict__ t_out){
    int wave = threadIdx.x >> 6, lane = threadIdx.x & 63;
    int mt = blockIdx.x*4 + wave;
    if(mt >= 3125) return;
    int m = lane & 15, q = lane >> 4;
    int row = init_ind[mt*16 + m];
    const float* ap = E + (long)row*DIM + q*8;
    float4v acc[8];
    #pragma unroll
    for(int i=0;i<8;i++) acc[i] = (float4v){0.f,0.f,0.f,0.f};
    #pragma unroll
    for(int ks=0; ks<4; ks++){
        float4v u0 = *(const float4v*)(ap + ks*32);
        float4v u1 = *(const float4v*)(ap + ks*32 + 4);
        half8 ah, al;
        #pragma unroll
        for(int j=0;j<8;j++){
            float fv = (j<4) ? u0[j] : u1[j-4];
            half_t h = (half_t)fv;
            ah[j] = h;
            al[j] = (half_t)(fv - (float)h);
        }
        #pragma unroll
        for(int nt=0; nt<8; nt++){
            half8 bh = *(const half8*)(WT_hi + (nt*16 + m)*DIM + ks*32 + q*8);
            half8 bl = *(const half8*)(WT_lo + (nt*16 + m)*DIM + ks*32 + q*8);
            acc[nt] = __builtin_amdgcn_mfma_f32_16x16x32_f16(ah, bh, acc[nt], 0,0,0);
            acc[nt] = __builtin_amdgcn_mfma_f32_16x16x32_f16(ah, bl, acc[nt], 0,0,0);
            acc[nt] = __builtin_amdgcn_mfma_f32_16x16x32_f16(al, bh, acc[nt], 0,0,0);
        }
    }
    #pragma unroll
    for(int nt=0; nt<8; nt++)
        #pragma unroll
        for(int r=0;r<4;r++)
            t_out[(mt*16 + q*4 + r)*DIM + nt*16 + m] = (half_t)acc[nt][r];
}

// ---------------- mm2: t = h @ W2, A pre-split fp16 ----------------
__global__ __launch_bounds__(256) void k_mm2(const half_t* __restrict__ h_hi,
                                             const half_t* __restrict__ h_lo,
                                             const half_t* __restrict__ WT_hi,
                                             const half_t* __restrict__ WT_lo,
                                             half_t* __restrict__ t_out){
    int wave = threadIdx.x >> 6, lane = threadIdx.x & 63;
    int mt = blockIdx.x*4 + wave;
    if(mt >= 3125) return;
    int m = lane & 15, q = lane >> 4;
    int row = mt*16 + m;
    const half_t* ah_p = h_hi + (long)row*DIM + q*8;
    const half_t* al_p = h_lo + (long)row*DIM + q*8;
    float4v acc[8];
    #pragma unroll
    for(int i=0;i<8;i++) acc[i] = (float4v){0.f,0.f,0.f,0.f};
    #pragma unroll
    for(int ks=0; ks<4; ks++){
        half8 ah = *(const half8*)(ah_p + ks*32);
        half8 al = *(const half8*)(al_p + ks*32);
        #pragma unroll
        for(int nt=0; nt<8; nt++){
            half8 bh = *(const half8*)(WT_hi + (nt*16 + m)*DIM + ks*32 + q*8);
            half8 bl = *(const half8*)(WT_lo + (nt*16 + m)*DIM + ks*32 + q*8);
            acc[nt] = __builtin_amdgcn_mfma_f32_16x16x32_f16(ah, bh, acc[nt], 0,0,0);
            acc[nt] = __builtin_amdgcn_mfma_f32_16x16x32_f16(ah, bl, acc[nt], 0,0,0);
            acc[nt] = __builtin_amdgcn_mfma_f32_16x16x32_f16(al, bh, acc[nt], 0,0,0);
        }
    }
    #pragma unroll
    for(int nt=0; nt<8; nt++)
        #pragma unroll
        for(int r=0;r<4;r++)
            t_out[(mt*16 + q*4 + r)*DIM + nt*16 + m] = (half_t)acc[nt][r];
}

// ---------------- SpMM: one wave/row, fp16 gathers (half2/lane), unroll 4 ----------------
__global__ __launch_bounds__(256) void k_spmm1(const half_t* __restrict__ t,
        const int* __restrict__ row_start, const int* __restrict__ csr_col,
        const float* __restrict__ csr_val, const float* __restrict__ b1,
        half_t* __restrict__ h_hi, half_t* __restrict__ h_lo){
    int wave = threadIdx.x>>6, lane = threadIdx.x&63;
    int i = blockIdx.x*4 + wave;
    if(i >= N_ENT) return;
    int e0 = __builtin_amdgcn_readfirstlane(row_start[i]);
    int e1 = __builtin_amdgcn_readfirstlane(row_start[i+1]);
    const half2v* tp = (const half2v*)t;
    float a0=0.f, a1=0.f;
    int e = e0;
    for(; e+4<=e1; e+=4){
        int c0=csr_col[e], c1=csr_col[e+1], c2=csr_col[e+2], c3=csr_col[e+3];
        float v0=csr_val[e], v1=csr_val[e+1], v2=csr_val[e+2], v3=csr_val[e+3];
        half2v p0=tp[c0*64+lane], p1=tp[c1*64+lane], p2=tp[c2*64+lane], p3=tp[c3*64+lane];
        a0 += v0*(float)p0[0]; a1 += v0*(float)p0[1];
        a0 += v1*(float)p1[0]; a1 += v1*(float)p1[1];
        a0 += v2*(float)p2[0]; a1 += v2*(float)p2[1];
        a0 += v3*(float)p3[0]; a1 += v3*(float)p3[1];
    }
    for(; e<e1; e++){
        int c = csr_col[e]; float v = csr_val[e];
        half2v p = tp[c*64+lane];
        a0 += v*(float)p[0]; a1 += v*(float)p[1];
    }
    float2v bb = *(const float2v*)(b1 + lane*2);
    float r0 = fmaxf(a0 + bb[0], 0.f);
    float r1 = fmaxf(a1 + bb[1], 0.f);
    half_t h0=(half_t)r0, h1=(half_t)r1;
    half2v hi = {h0, h1};
    half2v lo = {(half_t)(r0-(float)h0), (half_t)(r1-(float)h1)};
    *(half2v*)(h_hi + (long)i*DIM + lane*2) = hi;
    *(half2v*)(h_lo + (long)i*DIM + lane*2) = lo;
}

__global__ __launch_bounds__(256) void k_spmm2(const half_t* __restrict__ t,
        const int* __restrict__ row_start, const int* __restrict__ csr_col,
        const float* __restrict__ csr_val, const float* __restrict__ b2_,
        const float* __restrict__ E, const int* __restrict__ init_ind,
        half_t* __restrict__ fe_hi, half_t* __restrict__ fe_lo){
    int wave = threadIdx.x>>6, lane = threadIdx.x&63;
    int i = blockIdx.x*4 + wave;
    if(i >= N_ENT) return;
    int e0 = __builtin_amdgcn_readfirstlane(row_start[i]);
    int e1 = __builtin_amdgcn_readfirstlane(row_start[i+1]);
    const half2v* tp = (const half2v*)t;
    float a0=0.f, a1=0.f;
    int e = e0;
    for(; e+4<=e1; e+=4){
        int c0=csr_col[e], c1=csr_col[e+1], c2=csr_col[e+2], c3=csr_col[e+3];
        float v0=csr_val[e], v1=csr_val[e+1], v2=csr_val[e+2], v3=csr_val[e+3];
        half2v p0=tp[c0*64+lane], p1=tp[c1*64+lane], p2=tp[c2*64+lane], p3=tp[c3*64+lane];
        a0 += v0*(float)p0[0]; a1 += v0*(float)p0[1];
        a0 += v1*(float)p1[0]; a1 += v1*(float)p1[1];
        a0 += v2*(float)p2[0]; a1 += v2*(float)p2[1];
        a0 += v3*(float)p3[0]; a1 += v3*(float)p3[1];
    }
    for(; e<e1; e++){
        int c = csr_col[e]; float v = csr_val[e];
        half2v p = tp[c*64+lane];
        a0 += v*(float)p[0]; a1 += v*(float)p[1];
    }
    int erow = init_ind[i];
    float2v ev = *(const float2v*)(E + (long)erow*DIM + lane*2);
    float2v bb = *(const float2v*)(b2_ + lane*2);
    float f0 = ev[0] + fmaxf(a0 + bb[0], 0.f);
    float f1 = ev[1] + fmaxf(a1 + bb[1], 0.f);
    half_t h0=(half_t)f0, h1=(half_t)f1;
    half2v hi = {h0, h1};
    half2v lo = {(half_t)(f0-(float)h0), (half_t)(f1-(float)h1)};
    *(half2v*)(fe_hi + (long)i*DIM + lane*2) = hi;
    *(half2v*)(fe_lo + (long)i*DIM + lane*2) = lo;
}

// ---------------- vm = bn1(bn0(final[head]) * (R[rel]@W)), split fp16 ----------------
__global__ __launch_bounds__(128) void k_vm(const float* __restrict__ R_emb,
        const float* __restrict__ W, const int* __restrict__ head,
        const int* __restrict__ rel, const half_t* __restrict__ fe_hi,
        const half_t* __restrict__ fe_lo, const float* __restrict__ g0v,
        const float* __restrict__ be0, const float* __restrict__ g1v,
        const float* __restrict__ be1, half_t* __restrict__ vm_hi,
        half_t* __restrict__ vm_lo){
    int b = blockIdx.x; int j = threadIdx.x;
    __shared__ float rs[DIM];
    int rid = rel[b], hid = head[b];
    rs[j] = R_emb[rid*DIM + j];
    __syncthreads();
    float acc = 0.f;
    #pragma unroll 8
    for(int d=0; d<DIM; d++) acc += rs[d] * W[d*DIM + j];
    const float inv = rsqrtf(1.f + 1e-5f);
    float fe = (float)fe_hi[(long)hid*DIM+j] + (float)fe_lo[(long)hid*DIM+j];
    float x  = fe * (g0v[j] * inv) + be0[j];
    float vmv = (x * acc) * (g1v[j] * inv) + be1[j];
    half_t hi = (half_t)vmv;
    vm_hi[b*DIM+j] = hi;
    vm_lo[b*DIM+j] = (half_t)(vmv - (float)hi);
}

// ---------------- big GEMM: out = sigmoid(vm @ fe^T), 2-term fp16, LDS epilogue ----------------
__global__ __launch_bounds__(256) void k_big(const half_t* __restrict__ vm_hi,
        const half_t* __restrict__ vm_lo, const half_t* __restrict__ fe_h,
        float* __restrict__ out){
    __shared__ float sl[16*260];             // 16 rows x 260 stride (pad: conflict-free)
    int wave = threadIdx.x>>6, lane = threadIdx.x&63;
    int m = lane&15, q = lane>>4;
    int b0 = blockIdx.y * 64;                // 64 batch rows per block
    int n0 = blockIdx.x * 256 + wave*64;     // wave covers 64 entity cols
    float4v acc[4][4];
    #pragma unroll
    for(int a=0;a<4;a++)
        #pragma unroll
        for(int b=0;b<4;b++) acc[a][b] = (float4v){0.f,0.f,0.f,0.f};
    #pragma unroll
    for(int ks=0; ks<4; ks++){
        half8 B[4], Ah[4], Al[4];
        #pragma unroll
        for(int nt=0;nt<4;nt++){
            int nr = n0 + nt*16 + m;
            if(nr > N_ENT-1) nr = N_ENT-1;
            B[nt] = *(const half8*)(fe_h + (long)nr*DIM + ks*32 + q*8);
        }
        #pragma unroll
        for(int mt=0;mt<4;mt++){
            long ao = (long)(b0 + mt*16 + m)*DIM + ks*32 + q*8;
            Ah[mt] = *(const half8*)(vm_hi + ao);
            Al[mt] = *(const half8*)(vm_lo + ao);
        }
        #pragma unroll
        for(int mt=0;mt<4;mt++)
            #pragma unroll
            for(int nt=0;nt<4;nt++){
                acc[mt][nt] = __builtin_amdgcn_mfma_f32_16x16x32_f16(Ah[mt], B[nt], acc[mt][nt], 0,0,0);
                acc[mt][nt] = __builtin_amdgcn_mfma_f32_16x16x32_f16(Al[mt], B[nt], acc[mt][nt], 0,0,0);
            }
    }
    int gcol = blockIdx.x*256 + lane*4;
    #pragma unroll
    for(int mt=0; mt<4; mt++){
        if(mt) __syncthreads();
        #pragma unroll
        for(int nt=0;nt<4;nt++)
            #pragma unroll
            for(int r=0;r<4;r++){
                float d = acc[mt][nt][r];
                float s = __fdividef(1.f, 1.f + __expf(-d));
                sl[(q*4+r)*260 + wave*64 + nt*16 + m] = s;
            }
        __syncthreads();
        if(gcol < N_ENT){
            #pragma unroll
            for(int k=0;k<4;k++){
                int lr = wave*4 + k;
                float4v vv = *(const float4v*)&sl[lr*260 + lane*4];
                long off = (long)(b0 + mt*16 + lr)*N_ENT + gcol;
                __builtin_nontemporal_store(vv, (float4v*)(out + off));
            }
        }
    }
}

extern "C" void kernel_launch(void* const* d_in, const int* in_sizes, int n_in,
                              void* d_out, int out_size, void* d_ws, size_t ws_size,
                              hipStream_t stream) {
    const float* E     = (const float*)d_in[0];
    const float* R_emb = (const float*)d_in[1];
    const float* W1    = (const float*)d_in[2];
    const float* b1    = (const float*)d_in[3];
    const float* W2    = (const float*)d_in[4];
    const float* b2_   = (const float*)d_in[5];
    const float* W     = (const float*)d_in[6];
    const float* vals  = (const float*)d_in[7];
    const float* g0v   = (const float*)d_in[8];
    const float* be0   = (const float*)d_in[9];
    const float* g1v   = (const float*)d_in[10];
    const float* be1   = (const float*)d_in[11];
    const int* head    = (const int*)d_in[12];
    const int* rel     = (const int*)d_in[13];
    const int* init_ind= (const int*)d_in[14];
    const int* rows    = (const int*)d_in[15];
    const int* cols    = (const int*)d_in[16];
    float* out = (float*)d_out;

    char* w = (char*)d_ws;
    int*    deg       = (int*)   (w + 0);
    int*    cursor    = (int*)   (w + 200000);
    int*    row_start = (int*)   (w + 400000);
    int*    csr_col   = (int*)   (w + 600064);
    float*  csr_val   = (float*) (w + 3800064);
    half_t* W1T_hi    = (half_t*)(w + 7000064);
    half_t* W1T_lo    = (half_t*)(w + 7032832);
    half_t* W2T_hi    = (half_t*)(w + 7065600);
    half_t* W2T_lo    = (half_t*)(w + 7098368);
    half_t* t         = (half_t*)(w + 7131136);   // 12.8 MB fp16
    half_t* h_hi      = (half_t*)(w + 19931136);
    half_t* h_lo      = (half_t*)(w + 32731136);
    half_t* fe_hi     = (half_t*)(w + 45531136);
    half_t* fe_lo     = (half_t*)(w + 58331136);
    half_t* vm_hi     = (half_t*)(w + 71131136);
    half_t* vm_lo     = (half_t*)(w + 71393280);
    // end ~71.7 MB

    hipMemsetAsync(deg, 0, 2*N_ENT*sizeof(int), stream);   // deg + cursor
    k_hist    <<<3125, 256, 0, stream>>>(rows, deg);
    k_scan    <<<1, 1024, 0, stream>>>(deg, row_start);
    k_scatter <<<3125, 256, 0, stream>>>(rows, cols, vals, row_start, cursor, csr_col, csr_val);
    k_prep    <<<128, 256, 0, stream>>>(W1, W2, W1T_hi, W1T_lo, W2T_hi, W2T_lo);
    k_mm1     <<<782, 256, 0, stream>>>(E, init_ind, W1T_hi, W1T_lo, t);
    k_spmm1   <<<12500, 256, 0, stream>>>(t, row_start, csr_col, csr_val, b1, h_hi, h_lo);
    k_mm2     <<<782, 256, 0, stream>>>(h_hi, h_lo, W2T_hi, W2T_lo, t);
    k_spmm2   <<<12500, 256, 0, stream>>>(t, row_start, csr_col, csr_val, b2_, E, init_ind, fe_hi, fe_lo);
    k_vm      <<<BATCH, 128, 0, stream>>>(R_emb, W, head, rel, fe_hi, fe_lo, g0v, be0, g1v, be1, vm_hi, vm_lo);
    k_big     <<<dim3(196, 16), 256, 0, stream>>>(vm_hi, vm_lo, fe_hi, out);
}